// Round 9
// baseline (218.404 us; speedup 1.0000x reference)
//
#include <hip/hip_runtime.h>
#include <hip/hip_bf16.h>
#include <math.h>

// Problem constants (fixed by setup_inputs)
#define BATCH 4
#define NHEAD 8
#define HD 24          // head dim
#define CH 192         // total channels
#define HW 16384       // h*w
#define SPL 32         // kA col-blocks of 512
#define SROW 640       // Sp row: [0,576) gram, [576,600) sqq, [600,624) sqk, pad 640

// ws layout (floats):
//   Sp:  [32 bh][32 sp][640]    off 0        (2.62 MB)
//   Mo:  ushort[4][192][192]    off OFF_MO   (288 KB)
//   sem: uint[68]               off OFF_CNT  (cnt[32] | kcnt[32] | fin[4]; memset)
//   kbf: bf16[32 bh][24][16384] off OFF_KBF  (25.2 MB) — k pre-packed bf16
#define OFF_MO  (32 * SPL * SROW)
#define OFF_CNT (OFF_MO + (BATCH * CH * CH) / 2)
#define OFF_KBF 729600   // floats; 16B-aligned

#define LSTR 132    // u32 per kA LDS row (128 data + 4 pad)
#define KCN 64
#define BSTR3 100   // u32 per n-row of Bt: 96 data (192 ch as bf16 pairs) + 4 pad

typedef __attribute__((ext_vector_type(8)))  short bf16x8;
typedef __attribute__((ext_vector_type(16))) float f32x16;

__device__ __forceinline__ unsigned pack2(float a, float b) {
    union { __hip_bfloat162 h; unsigned u; } c;
    c.h = __float22bfloat162_rn(float2{a, b});
    return c.u;
}

// Agent-scope RELAXED accessors (sc1: commit at L3 coherence point, NO cache
// flush fences — the R3 ACQ_REL L2-writeback was a 47us disaster; this
// fenceless drain+counter recipe is verified in R4..R8).
__device__ __forceinline__ void st_agent(float* p, float v) {
    __hip_atomic_store(p, v, __ATOMIC_RELAXED, __HIP_MEMORY_SCOPE_AGENT);
}
__device__ __forceinline__ void st_agent_u(unsigned int* p, unsigned int v) {
    __hip_atomic_store(p, v, __ATOMIC_RELAXED, __HIP_MEMORY_SCOPE_AGENT);
}
__device__ __forceinline__ float ld_agent(const float* p) {
    return __hip_atomic_load(p, __ATOMIC_RELAXED, __HIP_MEMORY_SCOPE_AGENT);
}
__device__ __forceinline__ unsigned int ld_agent_u(const unsigned int* p) {
    return __hip_atomic_load(p, __ATOMIC_RELAXED, __HIP_MEMORY_SCOPE_AGENT);
}

// ---------------------------------------------------------------------------
// SINGLE persistent dispatch: 1024 blocks x 256 threads, exactly co-resident
// (25.6 KB LDS -> 4 blocks/CU). Per block:
//   phase 1 (kA unit, bh=bid>>5 cb=bid&31): gram partials + bf16 k export
//            (all cross-block data written sc1; per-wave vmcnt drain, then
//            relaxed counters cnt[bh], kcnt[cb])
//   phase 1b (last block of bh): finalizer -> Mo (sc1) ; fin[b]++
//   phase 2 (kC unit, b=bid>>8 nblk=bid&255): gate kcnt[cb']==32, stage Bt
//            from kbf; gate fin[b]==8; 36 MFMAs; out stores.
// Staging/stores of phase 2 overlap other blocks' phase-1 tails and the
// finalizer latency; one dispatch boundary is removed. Readers of kbf/Mo
// touch those addresses for the first time only after the gate -> no stale-L2
// hazard (first-touch rule), no read fences.
// ---------------------------------------------------------------------------
__global__ __launch_bounds__(256, 4) void fused(const float* __restrict__ q,
                                                const float* __restrict__ k,
                                                const float* __restrict__ scale,
                                                const float* __restrict__ w,
                                                float* __restrict__ ws,
                                                unsigned short* __restrict__ Mo,
                                                unsigned int* __restrict__ sem,
                                                unsigned int* __restrict__ kbf,
                                                float* __restrict__ out) {
    __shared__ unsigned int arena[KCN * BSTR3];   // 25.6 KB, phase-overlaid
    __shared__ int lastFlag;

    unsigned int* cnt  = sem;        // [32] per-bh kA completion
    unsigned int* kcnt = sem + 32;   // [32] per-cb kbf-column completion
    unsigned int* fin  = sem + 64;   // [4]  per-b Mo completion

    const int bid  = blockIdx.x;
    const int t    = threadIdx.x;
    const int lane = t & 63;
    const int wave = t >> 6;
    const int m    = lane & 31;
    const int hi   = lane >> 5;
    const int rowc = (m < HD) ? m : 0;   // clamp: garbage only hits discarded C

    // ===================== phase 1: kA unit =====================
    const int bh = bid >> 5;
    const int cb = bid & 31;
    {
        unsigned int (*tile)[HD * LSTR] = (unsigned int (*)[HD * LSTR])arena;
        f32x16 aQK = {}, aQQ = {}, aKK = {};

        #pragma unroll
        for (int half = 0; half < 2; ++half) {
            const float* qb = q + (size_t)bh * HD * HW + cb * 512 + half * 256;
            const float* kb = k + (size_t)bh * HD * HW + cb * 512 + half * 256;

            #pragma unroll
            for (int j = 0; j < 6; ++j) {
                const int idx = j * 256 + t;        // 0..1535
                const int row = idx >> 6;           // 0..23
                const int c64 = idx & 63;
                float4 qv = *(const float4*)(qb + (size_t)row * HW + c64 * 4);
                float4 kv = *(const float4*)(kb + (size_t)row * HW + c64 * 4);
                uint2 qp = make_uint2(pack2(qv.x, qv.y), pack2(qv.z, qv.w));
                uint2 kp = make_uint2(pack2(kv.x, kv.y), pack2(kv.z, kv.w));
                *(uint2*)&tile[0][row * LSTR + c64 * 2] = qp;
                *(uint2*)&tile[1][row * LSTR + c64 * 2] = kp;
                // Export packed k (sc1 -> L3) for phase-2 consumers.
                const size_t kidx = (((size_t)(bh * HD + row)) << 13) +
                                    (cb << 8) + half * 128 + (c64 << 1);
                st_agent_u(&kbf[kidx],     kp.x);
                st_agent_u(&kbf[kidx + 1], kp.y);
            }
            __syncthreads();

            #pragma unroll
            for (int s = 0; s < 4; ++s) {
                const int off = (wave * 64 + s * 16) >> 1;
                bf16x8 aq = *(const bf16x8*)&tile[0][rowc * LSTR + off + hi * 4];
                bf16x8 bk = *(const bf16x8*)&tile[1][rowc * LSTR + off + hi * 4];
                aQK = __builtin_amdgcn_mfma_f32_32x32x16_bf16(aq, bk, aQK, 0, 0, 0);
                aQQ = __builtin_amdgcn_mfma_f32_32x32x16_bf16(aq, aq, aQQ, 0, 0, 0);
                aKK = __builtin_amdgcn_mfma_f32_32x32x16_bf16(bk, bk, aKK, 0, 0, 0);
            }
            __syncthreads();
        }

        float* red = (float*)arena;
        if (m < HD) {
            #pragma unroll
            for (int r = 0; r < 16; ++r) {
                const int i = (r & 3) + 8 * (r >> 2) + 4 * hi;
                if (i < HD) {
                    red[wave * 624 + i * HD + m] = aQK[r];
                    if (i == m) {
                        red[wave * 624 + 576 + i] = aQQ[r];
                        red[wave * 624 + 600 + i] = aKK[r];
                    }
                }
            }
        }
        __syncthreads();

        float* Srow = ws + ((size_t)bh * SPL + cb) * SROW;
        for (int e = t; e < 624; e += 256)
            st_agent(&Srow[e], red[e] + red[624 + e] + red[1248 + e] + red[1872 + e]);

        // Per-wave drain: sc1 stores retire vmcnt at the L3 coherence point.
        asm volatile("s_waitcnt vmcnt(0)" ::: "memory");
        __syncthreads();

        if (t == 0) {
            unsigned int old = __hip_atomic_fetch_add(&cnt[bh], 1u,
                                                      __ATOMIC_RELAXED,
                                                      __HIP_MEMORY_SCOPE_AGENT);
            lastFlag = (old == SPL - 1);
            __hip_atomic_fetch_add(&kcnt[cb], 1u, __ATOMIC_RELAXED,
                                   __HIP_MEMORY_SCOPE_AGENT);
        }
        __syncthreads();
    }

    // ===================== phase 1b: finalizer =====================
    if (lastFlag) {
        // sf layout: [0,624) SA | [624,648) qinv | [648,672) kinv | [672,5280) wl
        float* sf = (float*)arena;
        const int b = bh >> 3;
        const int h = bh & 7;
        const float* base = ws + (size_t)bh * SPL * SROW;

        for (int idx = t; idx < CH * HD; idx += 256) {
            int o = idx / HD, dd = idx - o * HD;
            sf[672 + idx] = w[o * CH + h * HD + dd];
        }
        for (int e = t; e < 624; e += 256) {
            float s0 = 0.f, s1 = 0.f, s2 = 0.f, s3 = 0.f;
            #pragma unroll
            for (int sp = 0; sp < SPL; sp += 4) {
                s0 += ld_agent(&base[(size_t)(sp + 0) * SROW + e]);
                s1 += ld_agent(&base[(size_t)(sp + 1) * SROW + e]);
                s2 += ld_agent(&base[(size_t)(sp + 2) * SROW + e]);
                s3 += ld_agent(&base[(size_t)(sp + 3) * SROW + e]);
            }
            sf[e] = (s0 + s1) + (s2 + s3);
        }
        __syncthreads();

        if (t < 2 * HD) {
            float inv = 1.0f / fmaxf(sqrtf(sf[576 + t]), 1e-12f);
            sf[624 + t] = inv;                     // qinv at 624, kinv at 648
        }
        __syncthreads();

        const float sc = scale[h];
        for (int e = t; e < 576; e += 256)
            sf[e] = sf[e] * sf[624 + e / HD] * sf[648 + e % HD] * sc;
        __syncthreads();

        if (t < HD) {   // softmax along j for row t
            float mx = -1e30f;
            for (int j = 0; j < HD; ++j) mx = fmaxf(mx, sf[t * HD + j]);
            float sum = 0.f;
            for (int j = 0; j < HD; ++j) {
                float v = expf(sf[t * HD + j] - mx);
                sf[t * HD + j] = v;
                sum += v;
            }
            float r = 1.0f / sum;
            for (int j = 0; j < HD; ++j) sf[t * HD + j] *= r;
        }
        __syncthreads();

        // Mo[b][o][h*24 + 2jp,2jp+1] = (w-fold * attn) * kinv  (bf16 pairs, sc1)
        unsigned int* Mo32 = (unsigned int*)Mo;
        const size_t mobase = ((size_t)b * CH * CH + (size_t)h * HD) >> 1;
        for (int idx = t; idx < CH * HD / 2; idx += 256) {
            int o = idx / 12, jp = idx - o * 12;
            const int j0 = 2 * jp, j1 = 2 * jp + 1;
            float v0 = 0.f, v1 = 0.f;
            #pragma unroll
            for (int i = 0; i < HD; ++i) {
                const float wv = sf[672 + o * HD + i];
                v0 = fmaf(wv, sf[i * HD + j0], v0);
                v1 = fmaf(wv, sf[i * HD + j1], v1);
            }
            st_agent_u(&Mo32[mobase + (size_t)o * (CH / 2) + jp],
                       pack2(v0 * sf[648 + j0], v1 * sf[648 + j1]));
        }
        asm volatile("s_waitcnt vmcnt(0)" ::: "memory");
        __syncthreads();
        if (t == 0)
            __hip_atomic_fetch_add(&fin[b], 1u, __ATOMIC_RELAXED,
                                   __HIP_MEMORY_SCOPE_AGENT);
    }
    __syncthreads();   // arena free for phase-2 staging

    // ===================== phase 2: kC unit =====================
    const int bC   = bid >> 8;         // batch
    const int nblk = bid & 255;        // n-window (64 cols)
    const int cbC  = nblk >> 3;        // which kbf column block feeds this tile

    // Gate: kbf columns for this window fully exported (all 32 bh).
    if (t == 0) {
        while (ld_agent_u(&kcnt[cbC]) < (unsigned)SPL)
            __builtin_amdgcn_s_sleep(8);
    }
    __syncthreads();

    // Stage 64n x 192c bf16 tile from kbf (plain loads: first touch is
    // post-gate, data is at L3). 6 uint4 loads/thread.
    unsigned short* bt16 = (unsigned short*)arena;
    #pragma unroll
    for (int i = 0; i < 6; ++i) {
        const int idx = i * 256 + t;        // 0..1535
        const int ch  = idx >> 3;
        const int sl  = idx & 7;
        uint4 v4 = *(const uint4*)(kbf + (((size_t)(bC * CH + ch)) << 13) +
                                   ((size_t)nblk << 5) + (sl << 2));
        #pragma unroll
        for (int jj = 0; jj < 8; ++jj)
            bt16[(sl * 8 + jj) * (BSTR3 * 2) + ch] = ((const unsigned short*)&v4)[jj];
    }

    // Gate: Mo[b] complete (all 8 heads finalized).
    if (t == 0) {
        while (ld_agent_u(&fin[bC]) < (unsigned)NHEAD)
            __builtin_amdgcn_s_sleep(8);
    }
    __syncthreads();   // staging visible + Mo ready

    const unsigned short* Mob = Mo + (size_t)bC * CH * CH;
    const int n31 = lane & 31;
    const int nt  = wave & 1;           // n-tile (x32)
    const int otb = (wave >> 1) * 3;    // first o-tile (x32) of this wave

    f32x16 acc[3] = {};
    #pragma unroll
    for (int kc = 0; kc < 12; ++kc) {
        bf16x8 Bf = *(const bf16x8*)&arena[(nt * 32 + n31) * BSTR3 + kc * 8 + hi * 4];
        #pragma unroll
        for (int oi = 0; oi < 3; ++oi) {
            const unsigned short* ap =
                Mob + (size_t)((otb + oi) * 32 + n31) * CH + kc * 16 + hi * 8;
            bf16x8 Af = *(const bf16x8*)ap;
            acc[oi] = __builtin_amdgcn_mfma_f32_32x32x16_bf16(Af, Bf, acc[oi], 0, 0, 0);
        }
    }

    float* op = out + (size_t)bC * CH * HW;
    const int n = nblk * KCN + nt * 32 + n31;
    #pragma unroll
    for (int oi = 0; oi < 3; ++oi)
        #pragma unroll
        for (int r = 0; r < 16; ++r) {
            int o = (otb + oi) * 32 + (r & 3) + 8 * (r >> 2) + 4 * hi;
            op[(size_t)o * HW + n] = acc[oi][r];
        }
}

extern "C" void kernel_launch(void* const* d_in, const int* in_sizes, int n_in,
                              void* d_out, int out_size, void* d_ws, size_t ws_size,
                              hipStream_t stream) {
    const float* in1   = (const float*)d_in[0];
    const float* in2   = (const float*)d_in[1];
    const float* scale = (const float*)d_in[2];
    const float* projw = (const float*)d_in[3];
    float* ws  = (float*)d_ws;   // needs ~28.1 MB
    float* out = (float*)d_out;
    unsigned short* Mo = (unsigned short*)(ws + OFF_MO);
    unsigned int* sem  = (unsigned int*)(ws + OFF_CNT);
    unsigned int* kbf  = (unsigned int*)(ws + OFF_KBF);

    // ws is poisoned each iteration by the harness -> zero the 68 semaphores.
    hipMemsetAsync((void*)sem, 0, 68 * sizeof(unsigned int), stream);
    fused<<<1024, 256, 0, stream>>>(in1, in2, scale, projw, ws, Mo, sem, kbf, out);
}

// Round 10
// 178.948 us; speedup vs baseline: 1.2205x; 1.2205x over previous
//
#include <hip/hip_runtime.h>
#include <hip/hip_bf16.h>
#include <math.h>

// Problem constants (fixed by setup_inputs)
#define BATCH 4
#define NHEAD 8
#define HD 24          // head dim
#define CH 192         // total channels
#define HW 16384       // h*w
#define SPL 32         // kA col-blocks of 512
#define SROW 640       // Sp row: [0,576) gram, [576,600) sqq, [600,624) sqk, pad 640

// ws layout (floats):
//   Sp:  [32 bh][32 sp][640]   off 0        (2.62 MB)
//   Mo:  ushort[4][192][192]   off OFF_MO   (288 KB)
//   fin: uint[4]               off OFF_CNT  (zeroed via 16B memset each launch)
#define OFF_MO  (32 * SPL * SROW)
#define OFF_CNT (OFF_MO + (BATCH * CH * CH) / 2)

#define LSTR 132    // u32 per kA LDS row (128 data + 4 pad)
#define KCN 64
#define BSTR3 100   // u32 per n-row of Bt: 96 data (192 ch bf16 pairs) + 4 pad

typedef __attribute__((ext_vector_type(8)))  short bf16x8;
typedef __attribute__((ext_vector_type(16))) float f32x16;

__device__ __forceinline__ unsigned pack2(float a, float b) {
    union { __hip_bfloat162 h; unsigned u; } c;
    c.h = __float22bfloat162_rn(float2{a, b});
    return c.u;
}

// Agent-scope RELAXED accessors (sc1: commit at L3, no cache-flush fences —
// recipe verified R4..R9).
__device__ __forceinline__ void st_agent_u(unsigned int* p, unsigned int v) {
    __hip_atomic_store(p, v, __ATOMIC_RELAXED, __HIP_MEMORY_SCOPE_AGENT);
}
__device__ __forceinline__ unsigned int ld_agent_u(const unsigned int* p) {
    return __hip_atomic_load(p, __ATOMIC_RELAXED, __HIP_MEMORY_SCOPE_AGENT);
}

// ---------------------------------------------------------------------------
// Kernel A — PURE STREAM (finalizer moved to kC). Per (bh, 512-col block):
// two 256-col halves, coalesced fp32 loads -> bf16 LDS, MFMA gram 32x32x16
// accumulated in registers, cross-wave reduce, plain Srow store. No
// semaphores, no sc1 (dispatch boundary provides visibility to kC). This
// removes the 8-12us 224-CU-idle finalizer tail measured as kA's ~27%
// occupancy. grid (32 bh, 32 cb), block 256, 4/CU.
// ---------------------------------------------------------------------------
__global__ __launch_bounds__(256, 4) void kA(const float* __restrict__ q,
                                             const float* __restrict__ k,
                                             float* __restrict__ ws) {
    __shared__ unsigned int tile[2][HD * LSTR];   // 25.3 KB

    const int bh   = blockIdx.x;
    const int cb   = blockIdx.y;      // 0..31 -> cols [cb*512, cb*512+512)
    const int t    = threadIdx.x;
    const int lane = t & 63;
    const int wave = t >> 6;
    const int m    = lane & 31;
    const int hi   = lane >> 5;
    const int rowc = (m < HD) ? m : 0;   // clamp: garbage only hits discarded C

    f32x16 aQK = {}, aQQ = {}, aKK = {};

    #pragma unroll
    for (int half = 0; half < 2; ++half) {
        const float* qb = q + (size_t)bh * HD * HW + cb * 512 + half * 256;
        const float* kb = k + (size_t)bh * HD * HW + cb * 512 + half * 256;

        #pragma unroll
        for (int j = 0; j < 6; ++j) {
            const int idx = j * 256 + t;        // 0..1535
            const int row = idx >> 6;           // 0..23
            const int c64 = idx & 63;
            float4 qv = *(const float4*)(qb + (size_t)row * HW + c64 * 4);
            float4 kv = *(const float4*)(kb + (size_t)row * HW + c64 * 4);
            *(uint2*)&tile[0][row * LSTR + c64 * 2] =
                make_uint2(pack2(qv.x, qv.y), pack2(qv.z, qv.w));
            *(uint2*)&tile[1][row * LSTR + c64 * 2] =
                make_uint2(pack2(kv.x, kv.y), pack2(kv.z, kv.w));
        }
        __syncthreads();

        #pragma unroll
        for (int s = 0; s < 4; ++s) {
            const int off = (wave * 64 + s * 16) >> 1;
            bf16x8 aq = *(const bf16x8*)&tile[0][rowc * LSTR + off + hi * 4];
            bf16x8 bk = *(const bf16x8*)&tile[1][rowc * LSTR + off + hi * 4];
            aQK = __builtin_amdgcn_mfma_f32_32x32x16_bf16(aq, bk, aQK, 0, 0, 0);
            aQQ = __builtin_amdgcn_mfma_f32_32x32x16_bf16(aq, aq, aQQ, 0, 0, 0);
            aKK = __builtin_amdgcn_mfma_f32_32x32x16_bf16(bk, bk, aKK, 0, 0, 0);
        }
        __syncthreads();   // LDS reuse
    }

    float* red = (float*)tile;
    if (m < HD) {
        #pragma unroll
        for (int r = 0; r < 16; ++r) {
            const int i = (r & 3) + 8 * (r >> 2) + 4 * hi;
            if (i < HD) {
                red[wave * 624 + i * HD + m] = aQK[r];
                if (i == m) {
                    red[wave * 624 + 576 + i] = aQQ[r];
                    red[wave * 624 + 600 + i] = aKK[r];
                }
            }
        }
    }
    __syncthreads();

    float* Srow = ws + ((size_t)bh * SPL + cb) * SROW;
    for (int e = t; e < 624; e += 256)
        Srow[e] = red[e] + red[624 + e] + red[1248 + e] + red[1872 + e];
}

// ---------------------------------------------------------------------------
// Kernel C + embedded finalizer. Blocks with blockIdx.x < 8 FIRST finalize
// head bh = blockIdx.y*8 + blockIdx.x (Srow complete: prior dispatch):
// split-reduce, norms, softmax, proj_w fold -> Mo (sc1 + drain + fin[b]++).
// Meanwhile the other 1016 blocks stage their 64n x 192c in2 tile (the
// ~25us read phase) -> finalizer latency hides under staging instead of
// serializing between dispatches. All blocks then gate MFMA on fin[b]==8.
// grid (256, 4) = 1024 blocks, exactly co-resident (25.6KB LDS, 4/CU) ->
// gate is deadlock-free regardless of dispatch order.
// ---------------------------------------------------------------------------
__global__ __launch_bounds__(256, 4) void kC(const float* __restrict__ k,
                                             const float* __restrict__ scale,
                                             const float* __restrict__ w,
                                             const float* __restrict__ ws,
                                             unsigned short* __restrict__ Mo,
                                             unsigned int* __restrict__ fin,
                                             float* __restrict__ out) {
    __shared__ unsigned int arena[KCN * BSTR3];   // 25.6 KB (finalizer reuses)

    const int t    = threadIdx.x;
    const int lane = t & 63;
    const int wave = t >> 6;
    const int hi   = lane >> 5;
    const int nblk = blockIdx.x;
    const int bC   = blockIdx.y;

    // ---------------- finalizer (blocks x<8): bh = bC*8 + x ----------------
    if (nblk < NHEAD) {
        const int h  = nblk;
        const int bh = bC * NHEAD + h;
        // sf: [0,624) SA | [624,648) qinv | [648,672) kinv | [672,5280) wl
        float* sf = (float*)arena;
        const float* base = ws + (size_t)bh * SPL * SROW;

        for (int idx = t; idx < CH * HD; idx += 256) {
            int o = idx / HD, dd = idx - o * HD;
            sf[672 + idx] = w[o * CH + h * HD + dd];
        }
        for (int e = t; e < 624; e += 256) {
            float s0 = 0.f, s1 = 0.f, s2 = 0.f, s3 = 0.f;
            #pragma unroll
            for (int sp = 0; sp < SPL; sp += 4) {
                s0 += base[(size_t)(sp + 0) * SROW + e];
                s1 += base[(size_t)(sp + 1) * SROW + e];
                s2 += base[(size_t)(sp + 2) * SROW + e];
                s3 += base[(size_t)(sp + 3) * SROW + e];
            }
            sf[e] = (s0 + s1) + (s2 + s3);
        }
        __syncthreads();

        if (t < 2 * HD) {
            float inv = 1.0f / fmaxf(sqrtf(sf[576 + t]), 1e-12f);
            sf[624 + t] = inv;                     // qinv at 624, kinv at 648
        }
        __syncthreads();

        const float sc = scale[h];
        for (int e = t; e < 576; e += 256)
            sf[e] = sf[e] * sf[624 + e / HD] * sf[648 + e % HD] * sc;
        __syncthreads();

        if (t < HD) {   // softmax along j for row t
            float mx = -1e30f;
            for (int j = 0; j < HD; ++j) mx = fmaxf(mx, sf[t * HD + j]);
            float sum = 0.f;
            for (int j = 0; j < HD; ++j) {
                float v = expf(sf[t * HD + j] - mx);
                sf[t * HD + j] = v;
                sum += v;
            }
            float r = 1.0f / sum;
            for (int j = 0; j < HD; ++j) sf[t * HD + j] *= r;
        }
        __syncthreads();

        // Mo[b][o][h*24+2jp..+1] = (w-fold * attn) * kinv  (bf16 pairs, sc1)
        unsigned int* Mo32 = (unsigned int*)Mo;
        const size_t mobase = ((size_t)bC * CH * CH + (size_t)h * HD) >> 1;
        for (int idx = t; idx < CH * HD / 2; idx += 256) {
            int o = idx / 12, jp = idx - o * 12;
            const int j0 = 2 * jp, j1 = 2 * jp + 1;
            float v0 = 0.f, v1 = 0.f;
            #pragma unroll
            for (int i = 0; i < HD; ++i) {
                const float wv = sf[672 + o * HD + i];
                v0 = fmaf(wv, sf[i * HD + j0], v0);
                v1 = fmaf(wv, sf[i * HD + j1], v1);
            }
            st_agent_u(&Mo32[mobase + (size_t)o * (CH / 2) + jp],
                       pack2(v0 * sf[648 + j0], v1 * sf[648 + j1]));
        }
        asm volatile("s_waitcnt vmcnt(0)" ::: "memory");   // Mo at L3
        __syncthreads();
        if (t == 0)
            __hip_atomic_fetch_add(&fin[bC], 1u, __ATOMIC_RELAXED,
                                   __HIP_MEMORY_SCOPE_AGENT);
        __syncthreads();   // arena free for staging
    }

    // ---------------- staging: 64n x 192c tile from in2 (all blocks) ------
    const float* kb = k + (size_t)bC * CH * HW;
    const int nb  = nblk * KCN;
    const int np4 = t & 15;   // n-quad: rows np4*4 .. +3
    const int cg4 = t >> 4;   // 0..15: channels cg4*4 .. +3 per 64-ch stage

    #pragma unroll
    for (int s = 0; s < 3; ++s) {
        float4 v[4];
        #pragma unroll
        for (int cc = 0; cc < 4; ++cc)
            v[cc] = *(const float4*)(kb + (size_t)(s * 64 + cg4 * 4 + cc) * HW + nb + np4 * 4);
        #pragma unroll
        for (int r = 0; r < 4; ++r) {
            float x0 = (&v[0].x)[r], x1 = (&v[1].x)[r];
            float x2 = (&v[2].x)[r], x3 = (&v[3].x)[r];
            *(uint2*)&arena[(np4 * 4 + r) * BSTR3 + s * 32 + cg4 * 2] =
                make_uint2(pack2(x0, x1), pack2(x2, x3));
        }
    }

    // Gate: Mo[bC] complete (8 heads). Spin is ~0: finalizer << staging.
    if (t == 0) {
        while (ld_agent_u(&fin[bC]) < (unsigned)NHEAD)
            __builtin_amdgcn_s_sleep(8);
    }
    __syncthreads();   // staging visible + gate passed

    const unsigned short* Mob = Mo + (size_t)bC * CH * CH;
    const int n31 = lane & 31;
    const int nt  = wave & 1;           // n-tile (x32)
    const int otb = (wave >> 1) * 3;    // first o-tile (x32) of this wave

    f32x16 acc[3] = {};
    #pragma unroll
    for (int kc = 0; kc < 12; ++kc) {
        bf16x8 Bf = *(const bf16x8*)&arena[(nt * 32 + n31) * BSTR3 + kc * 8 + hi * 4];
        #pragma unroll
        for (int oi = 0; oi < 3; ++oi) {
            const unsigned short* ap =
                Mob + (size_t)((otb + oi) * 32 + n31) * CH + kc * 16 + hi * 8;
            bf16x8 Af = *(const bf16x8*)ap;
            acc[oi] = __builtin_amdgcn_mfma_f32_32x32x16_bf16(Af, Bf, acc[oi], 0, 0, 0);
        }
    }

    float* op = out + (size_t)bC * CH * HW;
    const int n = nb + nt * 32 + n31;
    #pragma unroll
    for (int oi = 0; oi < 3; ++oi)
        #pragma unroll
        for (int r = 0; r < 16; ++r) {
            int o = (otb + oi) * 32 + (r & 3) + 8 * (r >> 2) + 4 * hi;
            op[(size_t)o * HW + n] = acc[oi][r];
        }
}

extern "C" void kernel_launch(void* const* d_in, const int* in_sizes, int n_in,
                              void* d_out, int out_size, void* d_ws, size_t ws_size,
                              hipStream_t stream) {
    const float* in1   = (const float*)d_in[0];
    const float* in2   = (const float*)d_in[1];
    const float* scale = (const float*)d_in[2];
    const float* projw = (const float*)d_in[3];
    float* ws  = (float*)d_ws;   // needs ~2.9 MB
    float* out = (float*)d_out;
    unsigned short* Mo = (unsigned short*)(ws + OFF_MO);
    unsigned int* fin  = (unsigned int*)(ws + OFF_CNT);

    // ws is poisoned each iteration by the harness -> zero the 4 fin counters.
    hipMemsetAsync((void*)fin, 0, 4 * sizeof(unsigned int), stream);
    kA<<<dim3(32, SPL), 256, 0, stream>>>(in1, in2, ws);
    kC<<<dim3(HW / KCN, BATCH), 256, 0, stream>>>(in2, scale, projw, ws, Mo, fin, out);
}

// Round 11
// 174.717 us; speedup vs baseline: 1.2500x; 1.0242x over previous
//
#include <hip/hip_runtime.h>
#include <hip/hip_bf16.h>
#include <math.h>

// Problem constants (fixed by setup_inputs)
#define BATCH 4
#define NHEAD 8
#define HD 24          // head dim
#define CH 192         // total channels
#define HW 16384       // h*w
#define SPL 32         // kA col-blocks of 512 (2x256 cols accumulated in regs)
#define SROW 640       // Sp row: [0,576) gram, [576,600) sqq, [600,624) sqk, pad 640

// ws layout (floats):
//   Sp:  [32 bh][32 sp][640]   off 0        (2.62 MB)
//   Mo:  ushort[4][192][192]   off OFF_MO   (288 KB)
//   cnt: uint[32]              off OFF_CNT  (zeroed via tiny memset each launch)
#define OFF_MO  (32 * SPL * SROW)
#define OFF_CNT (OFF_MO + (BATCH * CH * CH) / 2)

#define LSTR 132   // u32 per kA LDS row (128 data + 4 pad)

typedef __attribute__((ext_vector_type(8)))  short bf16x8;
typedef __attribute__((ext_vector_type(16))) float f32x16;

__device__ __forceinline__ unsigned short bf16rne(float x) {
    union { float f; unsigned u; } v; v.f = x;
    unsigned u = v.u;
    return (unsigned short)((u + 0x7FFFu + ((u >> 16) & 1u)) >> 16);
}

__device__ __forceinline__ unsigned pack2(float a, float b) {
    union { __hip_bfloat162 h; unsigned u; } c;
    c.h = __float22bfloat162_rn(float2{a, b});
    return c.u;
}

// Agent-scope RELAXED accessors (sc1, commit at L3; NO cache-flush fences).
// R3 proved ACQ_REL's per-block L2 writeback costs 2x; this fenceless
// drain+counter recipe is verified across R4..R10.
__device__ __forceinline__ void st_agent(float* p, float v) {
    __hip_atomic_store(p, v, __ATOMIC_RELAXED, __HIP_MEMORY_SCOPE_AGENT);
}
__device__ __forceinline__ float ld_agent(const float* p) {
    return __hip_atomic_load(p, __ATOMIC_RELAXED, __HIP_MEMORY_SCOPE_AGENT);
}

// ---------------------------------------------------------------------------
// Kernel A + fenceless finalizer (best-measured config, R4: kA 43.6us).
// Per (bh, 512-col chunk): two 256-col sub-chunks, coalesced fp32 loads ->
// bf16 LDS tiles, MFMA Gram (32x32x16) accumulated in registers, one
// partial-row write (sc1). Per-wave vmcnt drain + barrier, then t0 does a
// RELAXED agent RMW on cnt[bh]; the block seeing old==SPL-1 runs the
// finalizer (split-reduce, norms, softmax, proj_w fold -> Mo bf16) inline.
// grid (32 bh, 32 ch), block 256, 4 blocks/CU.
// ---------------------------------------------------------------------------
__global__ __launch_bounds__(256, 4) void kA(const float* __restrict__ q,
                                             const float* __restrict__ k,
                                             const float* __restrict__ scale,
                                             const float* __restrict__ w,
                                             float* __restrict__ ws,
                                             unsigned short* __restrict__ Mo,
                                             unsigned int* __restrict__ cnt) {
    __shared__ unsigned int tile[2][HD * LSTR];   // 25.3 KB (reused by finalizer)
    __shared__ int lastFlag;

    const int bh   = blockIdx.x;
    const int ch   = blockIdx.y;      // 0..31 -> cols [ch*512, ch*512+512)
    const int t    = threadIdx.x;
    const int lane = t & 63;
    const int wave = t >> 6;
    const int m    = lane & 31;
    const int hi   = lane >> 5;
    const int rowc = (m < HD) ? m : 0;   // clamp: garbage only hits discarded C

    f32x16 aQK = {}, aQQ = {}, aKK = {};

    #pragma unroll
    for (int half = 0; half < 2; ++half) {
        const float* qb = q + (size_t)bh * HD * HW + ch * 512 + half * 256;
        const float* kb = k + (size_t)bh * HD * HW + ch * 512 + half * 256;

        #pragma unroll
        for (int j = 0; j < 6; ++j) {
            const int idx = j * 256 + t;        // 0..1535
            const int row = idx >> 6;           // 0..23
            const int c64 = idx & 63;
            float4 qv = *(const float4*)(qb + (size_t)row * HW + c64 * 4);
            float4 kv = *(const float4*)(kb + (size_t)row * HW + c64 * 4);
            *(uint2*)&tile[0][row * LSTR + c64 * 2] =
                make_uint2(pack2(qv.x, qv.y), pack2(qv.z, qv.w));
            *(uint2*)&tile[1][row * LSTR + c64 * 2] =
                make_uint2(pack2(kv.x, kv.y), pack2(kv.z, kv.w));
        }
        __syncthreads();

        #pragma unroll
        for (int s = 0; s < 4; ++s) {
            const int off = (wave * 64 + s * 16) >> 1;
            bf16x8 aq = *(const bf16x8*)&tile[0][rowc * LSTR + off + hi * 4];
            bf16x8 bk = *(const bf16x8*)&tile[1][rowc * LSTR + off + hi * 4];
            aQK = __builtin_amdgcn_mfma_f32_32x32x16_bf16(aq, bk, aQK, 0, 0, 0);
            aQQ = __builtin_amdgcn_mfma_f32_32x32x16_bf16(aq, aq, aQQ, 0, 0, 0);
            aKK = __builtin_amdgcn_mfma_f32_32x32x16_bf16(bk, bk, aKK, 0, 0, 0);
        }
        __syncthreads();   // LDS reuse (next half's staging / reduce scatter)
    }

    float* red = (float*)tile;
    if (m < HD) {
        #pragma unroll
        for (int r = 0; r < 16; ++r) {
            const int i = (r & 3) + 8 * (r >> 2) + 4 * hi;
            if (i < HD) {
                red[wave * 624 + i * HD + m] = aQK[r];
                if (i == m) {
                    red[wave * 624 + 576 + i] = aQQ[r];
                    red[wave * 624 + 600 + i] = aKK[r];
                }
            }
        }
    }
    __syncthreads();

    float* Srow = ws + ((size_t)bh * SPL + ch) * SROW;
    for (int e = t; e < 624; e += 256)
        st_agent(&Srow[e], red[e] + red[624 + e] + red[1248 + e] + red[1872 + e]);

    // Per-wave drain: sc1 stores retire vmcnt only when committed at the L3
    // coherence point, so after this they are agent-visible.
    asm volatile("s_waitcnt vmcnt(0)" ::: "memory");
    __syncthreads();   // all waves drained before t0's count increment

    if (t == 0) {
        unsigned int old = __hip_atomic_fetch_add(&cnt[bh], 1u,
                                                  __ATOMIC_RELAXED,
                                                  __HIP_MEMORY_SCOPE_AGENT);
        lastFlag = (old == SPL - 1);
    }
    __syncthreads();
    if (!lastFlag) return;

    // ---------------- finalizer (old kB), 256 threads, LDS reuse ----------
    // sf layout: [0,624) SA | [624,648) qinv | [648,672) kinv | [672,5280) wl
    float* sf = (float*)tile;
    const int b = bh >> 3;
    const int h = bh & 7;
    const float* base = ws + (size_t)bh * SPL * SROW;

    for (int idx = t; idx < CH * HD; idx += 256) {
        int o = idx / HD, dd = idx - o * HD;
        sf[672 + idx] = w[o * CH + h * HD + dd];
    }
    for (int e = t; e < 624; e += 256) {
        float s0 = 0.f, s1 = 0.f, s2 = 0.f, s3 = 0.f;
        #pragma unroll
        for (int sp = 0; sp < SPL; sp += 4) {
            s0 += ld_agent(&base[(size_t)(sp + 0) * SROW + e]);
            s1 += ld_agent(&base[(size_t)(sp + 1) * SROW + e]);
            s2 += ld_agent(&base[(size_t)(sp + 2) * SROW + e]);
            s3 += ld_agent(&base[(size_t)(sp + 3) * SROW + e]);
        }
        sf[e] = (s0 + s1) + (s2 + s3);
    }
    __syncthreads();

    if (t < 2 * HD) {
        float inv = 1.0f / fmaxf(sqrtf(sf[576 + t]), 1e-12f);
        sf[624 + t] = inv;                     // qinv at 624, kinv at 648
    }
    __syncthreads();

    const float sc = scale[h];
    for (int e = t; e < 576; e += 256)
        sf[e] = sf[e] * sf[624 + e / HD] * sf[648 + e % HD] * sc;
    __syncthreads();

    if (t < HD) {   // softmax along j for row t
        float mx = -1e30f;
        for (int j = 0; j < HD; ++j) mx = fmaxf(mx, sf[t * HD + j]);
        float sum = 0.f;
        for (int j = 0; j < HD; ++j) {
            float v = expf(sf[t * HD + j] - mx);
            sf[t * HD + j] = v;
            sum += v;
        }
        float r = 1.0f / sum;
        for (int j = 0; j < HD; ++j) sf[t * HD + j] *= r;
    }
    __syncthreads();

    // Mo[b][o][h*24+j] = (sum_i w[o,h*24+i] * attn[i][j]) * kinv[j]  (bf16)
    // Mo is consumed by the NEXT dispatch (kC): end-of-kernel writeback
    // handles cross-XCD visibility; plain stores are fine here.
    for (int idx = t; idx < CH * HD; idx += 256) {
        int o = idx / HD, j = idx - o * HD;
        float v = 0.f;
        #pragma unroll
        for (int i = 0; i < HD; ++i)
            v = fmaf(sf[672 + o * HD + i], sf[i * HD + j], v);
        Mo[(size_t)b * CH * CH + (size_t)o * CH + h * HD + j] = bf16rne(v * sf[648 + j]);
    }
}

// ---------------------------------------------------------------------------
// Kernel C: out[b][o][n] = sum_c Mo[b][o][c] * in2[b][c][n]  via mfma_32x32x16.
// Block tile O=192 x N=64. Single-shot staging: the ENTIRE 64n x 192c k-tile
// is loaded up-front with 12 float4 loads/thread (1 KB/wave segments, deep
// MLP), ONE barrier, then 36 back-to-back MFMAs. grid (256 nblk, 4 b),
// block 256, 4 blocks/CU.
// ---------------------------------------------------------------------------
#define KCN 64
#define BSTR3 100   // u32 per n-row: 96 data (192 ch as bf16 pairs) + 4 pad

__global__ __launch_bounds__(256, 4) void kC(const float* __restrict__ k,
                                             const unsigned short* __restrict__ Mo,
                                             float* __restrict__ out) {
    __shared__ unsigned int Bt[KCN * BSTR3];   // 25.6 KB

    const int t    = threadIdx.x;
    const int lane = t & 63;
    const int wave = t >> 6;
    const int n31  = lane & 31;
    const int hi   = lane >> 5;
    const int nt   = wave & 1;          // n-tile (x32)
    const int otb  = (wave >> 1) * 3;   // first o-tile (x32) of this wave

    const int nb = blockIdx.x * KCN;
    const int b  = blockIdx.y;

    const float* kb = k + (size_t)b * CH * HW;
    const unsigned short* Mob = Mo + (size_t)b * CH * CH;

    const int np4 = t & 15;   // n-quad: rows np4*4 .. +3
    const int cg4 = t >> 4;   // 0..15: channels cg4*4 .. +3 per 64-ch stage

    // Stage the whole 64 x 192 tile (fp32 -> bf16 pairs), one barrier.
    #pragma unroll
    for (int s = 0; s < 3; ++s) {
        float4 v[4];
        #pragma unroll
        for (int cc = 0; cc < 4; ++cc)
            v[cc] = *(const float4*)(kb + (size_t)(s * 64 + cg4 * 4 + cc) * HW + nb + np4 * 4);
        #pragma unroll
        for (int r = 0; r < 4; ++r) {
            float x0 = (&v[0].x)[r], x1 = (&v[1].x)[r];
            float x2 = (&v[2].x)[r], x3 = (&v[3].x)[r];
            *(uint2*)&Bt[(np4 * 4 + r) * BSTR3 + s * 32 + cg4 * 2] =
                make_uint2(pack2(x0, x1), pack2(x2, x3));
        }
    }
    __syncthreads();

    f32x16 acc[3] = {};
    #pragma unroll
    for (int kc = 0; kc < 12; ++kc) {
        bf16x8 Bf = *(const bf16x8*)&Bt[(nt * 32 + n31) * BSTR3 + kc * 8 + hi * 4];
        #pragma unroll
        for (int oi = 0; oi < 3; ++oi) {
            const unsigned short* ap =
                Mob + (size_t)((otb + oi) * 32 + n31) * CH + kc * 16 + hi * 8;
            bf16x8 Af = *(const bf16x8*)ap;
            acc[oi] = __builtin_amdgcn_mfma_f32_32x32x16_bf16(Af, Bf, acc[oi], 0, 0, 0);
        }
    }

    float* op = out + (size_t)b * CH * HW;
    const int n = nb + nt * 32 + n31;
    #pragma unroll
    for (int oi = 0; oi < 3; ++oi)
        #pragma unroll
        for (int r = 0; r < 16; ++r) {
            int o = (otb + oi) * 32 + (r & 3) + 8 * (r >> 2) + 4 * hi;
            op[(size_t)o * HW + n] = acc[oi][r];
        }
}

extern "C" void kernel_launch(void* const* d_in, const int* in_sizes, int n_in,
                              void* d_out, int out_size, void* d_ws, size_t ws_size,
                              hipStream_t stream) {
    const float* in1   = (const float*)d_in[0];
    const float* in2   = (const float*)d_in[1];
    const float* scale = (const float*)d_in[2];
    const float* projw = (const float*)d_in[3];
    float* ws  = (float*)d_ws;   // needs ~2.9 MB
    float* out = (float*)d_out;
    unsigned short* Mo = (unsigned short*)(ws + OFF_MO);
    unsigned int* cnt  = (unsigned int*)(ws + OFF_CNT);

    // ws is poisoned each iteration by the harness -> zero the 32 semaphores.
    hipMemsetAsync((void*)cnt, 0, 32 * sizeof(unsigned int), stream);
    kA<<<dim3(32, SPL), 256, 0, stream>>>(in1, in2, scale, projw, ws, Mo, cnt);
    kC<<<dim3(HW / KCN, BATCH), 256, 0, stream>>>(in2, Mo, out);
}